// Round 1
// baseline (264.102 us; speedup 1.0000x reference)
//
#include <hip/hip_runtime.h>

typedef _Float16 f16;
typedef _Float16 f16x4 __attribute__((ext_vector_type(4)));
typedef _Float16 f16x8 __attribute__((ext_vector_type(8)));
typedef float f32x4 __attribute__((ext_vector_type(4)));

constexpr int SP = 65536;  // 16^4

// ---------------------------------------------------------------------------
// Weight transform: fp32 [Cout][Cin][3][3][3][3] -> f16 [81][CoutP][Cin]
// (tap-major, ci contiguous). Layer1 -> [32][96] (k = tap, zero-padded 81..95).
// Layer4 Cout padded 1 -> 16 with zeros.
// Half-element offsets inside ws:
//   w1t: [0, 3072)        32*96
//   w2t: [3072, 168960)   81*64*32
//   w3t: [168960, 334848) 81*32*64
//   w4t: [334848, 376320) 81*16*32
//   a1 : [376320, ...)    2*SP*32 channels-last
//   a2 : a1 + 4194304     2*SP*64 channels-last
//   a3 : aliases a1
// Total ws use: 25,918,464 bytes.
// ---------------------------------------------------------------------------
__global__ __launch_bounds__(256) void wtrans_k(
    const float* __restrict__ w1, const float* __restrict__ w2,
    const float* __restrict__ w3, const float* __restrict__ w4,
    f16* __restrict__ wt)
{
  int i = blockIdx.x * 256 + threadIdx.x;
  if (i < 3072) {
    int co = i / 96, k = i - co * 96;
    wt[i] = (k < 81) ? (f16)w1[co * 81 + k] : (f16)0.f;
  } else if (i < 168960) {
    int j = i - 3072;
    int t = j >> 11, r = j & 2047;
    int co = r >> 5, ci = r & 31;
    wt[i] = (f16)w2[(co * 32 + ci) * 81 + t];
  } else if (i < 334848) {
    int j = i - 168960;
    int t = j >> 11, r = j & 2047;
    int co = r >> 6, ci = r & 63;
    wt[i] = (f16)w3[(co * 64 + ci) * 81 + t];
  } else if (i < 376320) {
    int j = i - 334848;
    int t = j >> 9, r = j & 511;
    int co = r >> 5, ci = r & 31;
    wt[i] = (co == 0) ? (f16)w4[ci * 81 + t] : (f16)0.f;
  }
}

// ---------------------------------------------------------------------------
// Layer 1: Cin=1, Cout=32. x fp32 standard layout -> a1 f16 channels-last.
// GEMM: M=32 (co), N=256 (plane), K=96 (81 taps padded). One block per
// (b,d1,d2) plane. B expanded in LDS from a 4D halo.
// ---------------------------------------------------------------------------
__global__ __launch_bounds__(256) void conv_l1_k(
    const float* __restrict__ x, const f16* __restrict__ w1t,
    const float* __restrict__ bias, f16* __restrict__ aout)
{
  __shared__ float H1[9 * 324];      // [e1*3+e2][h3][h4], 18x18 halo planes
  __shared__ f16 Bexp[256 * 104];    // [n][k], stride 104 halves (16B aligned)
  const int tid = threadIdx.x, bid = blockIdx.x;
  const int b = bid >> 8;
  const int d1 = (bid >> 4) & 15, d2 = bid & 15;
  const float* xb = x + b * SP;

  for (int idx = tid; idx < 9 * 324; idx += 256) {
    int e = idx / 324, c = idx - e * 324;
    int h3 = c / 18, h4 = c - h3 * 18;
    int e1 = e / 3, e2 = e - e1 * 3;
    int dd1 = d1 + e1 - 1, dd2 = d2 + e2 - 1;
    int dd3 = h3 - 1, dd4 = h4 - 1;
    float v = 0.f;
    if (((unsigned)dd1 < 16u) & ((unsigned)dd2 < 16u) &
        ((unsigned)dd3 < 16u) & ((unsigned)dd4 < 16u))
      v = xb[((dd1 * 16 + dd2) * 16 + dd3) * 16 + dd4];
    H1[idx] = v;
  }
  __syncthreads();
  {
    int d3 = tid >> 4, d4 = tid & 15;
    f16* bp = Bexp + tid * 104;
    #pragma unroll
    for (int k = 0; k < 96; ++k) {
      float v = 0.f;
      if (k < 81) {
        int e = k / 9, rem = k - e * 9;
        int o3 = rem / 3, o4 = rem - o3 * 3;
        v = H1[e * 324 + (d3 + o3) * 18 + (d4 + o4)];
      }
      bp[k] = (f16)v;
    }
  }
  __syncthreads();

  const int lane = tid & 63, wave = tid >> 6;
  const int lm = lane & 15, kp = lane >> 4;
  f32x4 acc[2][4] = {};
  #pragma unroll
  for (int k0 = 0; k0 < 96; k0 += 32) {
    f16x8 a0 = *(const f16x8*)(w1t + lm * 96 + k0 + kp * 8);
    f16x8 a1 = *(const f16x8*)(w1t + (16 + lm) * 96 + k0 + kp * 8);
    #pragma unroll
    for (int nt = 0; nt < 4; ++nt) {
      int n = (wave * 4 + nt) * 16 + lm;
      f16x8 bf = *(const f16x8*)(Bexp + n * 104 + k0 + kp * 8);
      acc[0][nt] = __builtin_amdgcn_mfma_f32_16x16x32_f16(a0, bf, acc[0][nt], 0, 0, 0);
      acc[1][nt] = __builtin_amdgcn_mfma_f32_16x16x32_f16(a1, bf, acc[1][nt], 0, 0, 0);
    }
  }
  // epilogue: bias + relu, channels-last store [pos][32]
  #pragma unroll
  for (int mt = 0; mt < 2; ++mt) {
    int co = mt * 16 + kp * 4;
    const float* bp = bias + co;
    #pragma unroll
    for (int nt = 0; nt < 4; ++nt) {
      int d3 = wave * 4 + nt;
      f16x4 pk;
      #pragma unroll
      for (int r = 0; r < 4; ++r)
        pk[r] = (f16)fmaxf(acc[mt][nt][r] + bp[r], 0.f);
      *(f16x4*)(aout + (bid * 256 + d3 * 16 + lm) * 32 + co) = pk;
    }
  }
}

// ---------------------------------------------------------------------------
// Layers 2..4: channels-last f16 in, tap-decomposed implicit GEMM.
// One block per (b,d1,d2) plane, 4 waves; wave w owns d3 rows 4w..4w+3.
// Per (ci-chunk, e1,e2): stage 18x18x32 halo plane (padded LDS), then 9
// (o3,o4) taps x K=32 MFMA. A-fragments read from transformed weights (L2).
// ---------------------------------------------------------------------------
template<int CIN, int COUTP, bool RELU, bool FINAL>
__global__ __launch_bounds__(256) void conv_layer_k(
    const f16* __restrict__ ain, const f16* __restrict__ wt,
    const float* __restrict__ bias, f16* __restrict__ aout,
    float* __restrict__ fout)
{
  constexpr int MT = COUTP / 16;
  constexpr int STRIDE = 40;               // halves per halo cell (16B aligned)
  __shared__ f16 hal[324 * STRIDE];        // 25,920 B

  const int tid = threadIdx.x, bid = blockIdx.x;
  const int b = bid >> 8;
  const int d1 = (bid >> 4) & 15, d2 = bid & 15;
  const int lane = tid & 63, wave = tid >> 6;
  const int lm = lane & 15, kp = lane >> 4;

  f32x4 acc[MT][4] = {};

  for (int ck = 0; ck < CIN / 32; ++ck) {
    for (int e = 0; e < 9; ++e) {
      int e1 = e / 3, e2 = e - e1 * 3;
      __syncthreads();
      // ---- stage halo plane: 324 cells x 32 ci (64B each) ----
      {
        int dd1 = d1 + e1 - 1, dd2 = d2 + e2 - 1;
        bool pok = ((unsigned)dd1 < 16u) && ((unsigned)dd2 < 16u);
        const f16* src0 = ain + (size_t)(((b * 16 + dd1) * 16 + dd2) * 256) * CIN + ck * 32;
        for (int c = tid; c < 324; c += 256) {
          int h3 = c / 18, h4 = c - h3 * 18;
          int dd3 = h3 - 1, dd4 = h4 - 1;
          bool ok = pok && ((unsigned)dd3 < 16u) && ((unsigned)dd4 < 16u);
          int4 v0 = {0,0,0,0}, v1 = {0,0,0,0}, v2 = {0,0,0,0}, v3 = {0,0,0,0};
          if (ok) {
            const int4* p = (const int4*)(src0 + (dd3 * 16 + dd4) * CIN);
            v0 = p[0]; v1 = p[1]; v2 = p[2]; v3 = p[3];
          }
          int4* dst = (int4*)(hal + c * STRIDE);
          dst[0] = v0; dst[1] = v1; dst[2] = v2; dst[3] = v3;
        }
      }
      __syncthreads();
      // ---- 9 taps on this plane ----
      for (int o3 = 0; o3 < 3; ++o3) {
        for (int o4 = 0; o4 < 3; ++o4) {
          int tap = (e * 3 + o3) * 3 + o4;
          f16x8 a[MT];
          #pragma unroll
          for (int mt = 0; mt < MT; ++mt)
            a[mt] = *(const f16x8*)(wt + (size_t)(tap * COUTP + mt * 16 + lm) * CIN + ck * 32 + kp * 8);
          #pragma unroll
          for (int nt = 0; nt < 4; ++nt) {
            int h3 = wave * 4 + nt + o3, h4 = lm + o4;
            f16x8 bf = *(const f16x8*)(hal + (h3 * 18 + h4) * STRIDE + kp * 8);
            #pragma unroll
            for (int mt = 0; mt < MT; ++mt)
              acc[mt][nt] = __builtin_amdgcn_mfma_f32_16x16x32_f16(a[mt], bf, acc[mt][nt], 0, 0, 0);
          }
        }
      }
    }
  }

  // ---- epilogue ----
  if (FINAL) {
    if (kp == 0) {               // co row 0 lives in lanes 0..15, reg 0
      float bv = bias[0];
      #pragma unroll
      for (int nt = 0; nt < 4; ++nt) {
        int d3 = wave * 4 + nt;
        fout[bid * 256 + d3 * 16 + lm] = acc[0][nt][0] + bv;
      }
    }
  } else {
    #pragma unroll
    for (int mt = 0; mt < MT; ++mt) {
      int co = mt * 16 + kp * 4;
      const float* bp = bias + co;
      #pragma unroll
      for (int nt = 0; nt < 4; ++nt) {
        int d3 = wave * 4 + nt;
        f16x4 pk;
        #pragma unroll
        for (int r = 0; r < 4; ++r) {
          float v = acc[mt][nt][r] + bp[r];
          if (RELU) v = fmaxf(v, 0.f);
          pk[r] = (f16)v;
        }
        *(f16x4*)(aout + (size_t)(bid * 256 + d3 * 16 + lm) * COUTP + co) = pk;
      }
    }
  }
}

extern "C" void kernel_launch(void* const* d_in, const int* in_sizes, int n_in,
                              void* d_out, int out_size, void* d_ws, size_t ws_size,
                              hipStream_t stream)
{
  (void)in_sizes; (void)n_in; (void)out_size; (void)ws_size;
  const float* x  = (const float*)d_in[0];
  const float* w1 = (const float*)d_in[1];
  const float* b1 = (const float*)d_in[2];
  const float* w2 = (const float*)d_in[3];
  const float* b2 = (const float*)d_in[4];
  const float* w3 = (const float*)d_in[5];
  const float* b3 = (const float*)d_in[6];
  const float* w4 = (const float*)d_in[7];
  const float* b4 = (const float*)d_in[8];

  f16* ws  = (f16*)d_ws;
  f16* w1t = ws;
  f16* w2t = ws + 3072;
  f16* w3t = ws + 168960;
  f16* w4t = ws + 334848;
  f16* a1  = ws + 376320;
  f16* a2  = a1 + (size_t)2 * SP * 32;
  f16* a3  = a1;                      // a1 dead after layer 2 reads it
  float* out = (float*)d_out;

  wtrans_k<<<1470, 256, 0, stream>>>(w1, w2, w3, w4, ws);
  conv_l1_k<<<512, 256, 0, stream>>>(x, w1t, b1, a1);
  conv_layer_k<32, 64, true,  false><<<512, 256, 0, stream>>>(a1, w2t, b2, a2, nullptr);
  conv_layer_k<64, 32, true,  false><<<512, 256, 0, stream>>>(a2, w3t, b3, a3, nullptr);
  conv_layer_k<32, 16, false, true ><<<512, 256, 0, stream>>>(a3, w4t, b4, nullptr, out);
}

// Round 3
// 240.680 us; speedup vs baseline: 1.0973x; 1.0973x over previous
//
#include <hip/hip_runtime.h>

typedef _Float16 f16;
typedef _Float16 f16x4 __attribute__((ext_vector_type(4)));
typedef _Float16 f16x8 __attribute__((ext_vector_type(8)));
typedef float f32x4 __attribute__((ext_vector_type(4)));
typedef int int4v __attribute__((ext_vector_type(4)));

constexpr int SP = 65536;  // 16^4

#define GLD16(g, l) __builtin_amdgcn_global_load_lds( \
  (const __attribute__((address_space(1))) void*)(g), \
  (__attribute__((address_space(3))) void*)(l), 16, 0, 0)

// ---------------------------------------------------------------------------
// Weight transform: fp32 [Cout][Cin][3^4] -> f16 [81][CoutP][Cin].
// Layer1 -> [32][96] (k = tap, zero-padded 81..95). Layer4 Cout 1 -> 16 pad.
// Half-element ws offsets: w1t 0 / w2t 3072 / w3t 168960 / w4t 334848 /
// a1 376320 / a2 4570624 (a3 aliases a1). Total 25,918,464 B.
// ---------------------------------------------------------------------------
__global__ __launch_bounds__(256) void wtrans_k(
    const float* __restrict__ w1, const float* __restrict__ w2,
    const float* __restrict__ w3, const float* __restrict__ w4,
    f16* __restrict__ wt)
{
  int i = blockIdx.x * 256 + threadIdx.x;
  if (i < 3072) {
    int co = i / 96, k = i - co * 96;
    wt[i] = (k < 81) ? (f16)w1[co * 81 + k] : (f16)0.f;
  } else if (i < 168960) {
    int j = i - 3072;
    int t = j >> 11, r = j & 2047;
    int co = r >> 5, ci = r & 31;
    wt[i] = (f16)w2[(co * 32 + ci) * 81 + t];
  } else if (i < 334848) {
    int j = i - 168960;
    int t = j >> 11, r = j & 2047;
    int co = r >> 6, ci = r & 63;
    wt[i] = (f16)w3[(co * 64 + ci) * 81 + t];
  } else if (i < 376320) {
    int j = i - 334848;
    int t = j >> 9, r = j & 511;
    int co = r >> 5, ci = r & 31;
    wt[i] = (co == 0) ? (f16)w4[ci * 81 + t] : (f16)0.f;
  }
}

// XCD-aware swizzle for 512 blocks: XCD k (= raw%8) gets contiguous chunk of
// 64 (b,d1,d2) triples -> per-XCD input footprint <= 3 MB, fits 4 MB L2.
__device__ inline int xcd_swizzle(int raw) { return (raw & 7) * 64 + (raw >> 3); }

// ---------------------------------------------------------------------------
// Layer 1: Cin=1, Cout=32, fp32 in -> f16 channels-last out.
// ---------------------------------------------------------------------------
__global__ __launch_bounds__(256) void conv_l1_k(
    const float* __restrict__ x, const f16* __restrict__ w1t,
    const float* __restrict__ bias, f16* __restrict__ aout)
{
  __shared__ float H1[9 * 324];
  __shared__ f16 Bexp[256 * 104];
  const int tid = threadIdx.x;
  const int bid = xcd_swizzle(blockIdx.x);
  const int b = bid >> 8;
  const int d1 = (bid >> 4) & 15, d2 = bid & 15;
  const float* xb = x + b * SP;

  for (int idx = tid; idx < 9 * 324; idx += 256) {
    int e = idx / 324, c = idx - e * 324;
    int h3 = c / 18, h4 = c - h3 * 18;
    int e1 = e / 3, e2 = e - e1 * 3;
    int dd1 = d1 + e1 - 1, dd2 = d2 + e2 - 1;
    int dd3 = h3 - 1, dd4 = h4 - 1;
    float v = 0.f;
    if (((unsigned)dd1 < 16u) & ((unsigned)dd2 < 16u) &
        ((unsigned)dd3 < 16u) & ((unsigned)dd4 < 16u))
      v = xb[((dd1 * 16 + dd2) * 16 + dd3) * 16 + dd4];
    H1[idx] = v;
  }
  __syncthreads();
  {
    int d3 = tid >> 4, d4 = tid & 15;
    f16* bp = Bexp + tid * 104;
    #pragma unroll
    for (int k = 0; k < 96; ++k) {
      float v = 0.f;
      if (k < 81) {
        int e = k / 9, rem = k - e * 9;
        int o3 = rem / 3, o4 = rem - o3 * 3;
        v = H1[e * 324 + (d3 + o3) * 18 + (d4 + o4)];
      }
      bp[k] = (f16)v;
    }
  }
  __syncthreads();

  const int lane = tid & 63, wave = tid >> 6;
  const int lm = lane & 15, kp = lane >> 4;
  f32x4 acc[2][4] = {};
  #pragma unroll
  for (int k0 = 0; k0 < 96; k0 += 32) {
    f16x8 a0 = *(const f16x8*)(w1t + lm * 96 + k0 + kp * 8);
    f16x8 a1 = *(const f16x8*)(w1t + (16 + lm) * 96 + k0 + kp * 8);
    #pragma unroll
    for (int nt = 0; nt < 4; ++nt) {
      int n = (wave * 4 + nt) * 16 + lm;
      f16x8 bf = *(const f16x8*)(Bexp + n * 104 + k0 + kp * 8);
      acc[0][nt] = __builtin_amdgcn_mfma_f32_16x16x32_f16(a0, bf, acc[0][nt], 0, 0, 0);
      acc[1][nt] = __builtin_amdgcn_mfma_f32_16x16x32_f16(a1, bf, acc[1][nt], 0, 0, 0);
    }
  }
  #pragma unroll
  for (int mt = 0; mt < 2; ++mt) {
    int co = mt * 16 + kp * 4;
    const float* bp = bias + co;
    #pragma unroll
    for (int nt = 0; nt < 4; ++nt) {
      int d3 = wave * 4 + nt;
      f16x4 pk;
      #pragma unroll
      for (int r = 0; r < 4; ++r)
        pk[r] = (f16)fmaxf(acc[mt][nt][r] + bp[r], 0.f);
      *(f16x4*)(aout + (bid * 256 + d3 * 16 + lm) * 32 + co) = pk;
    }
  }
}

// ---------------------------------------------------------------------------
// Layers 2..4: tap-decomposed implicit GEMM, double-buffered LDS halo staged
// via global_load_lds (linear 64B cells), raw s_barrier + counted vmcnt so
// the next stage's loads stay in flight across the barrier.
// Stage s = (ck, e1*3+e2): 18x18 halo plane of 32 ci halves per cell.
// Wave w stages cells [81w, 81w+81); overflow chunk-lanes duplicate the next
// wave's first cells (identical data -> benign) or fall OOB (dd3>=16 ->
// zeroed via divergent ds_write). Compute: 9 (o3,o4) taps x 4 nt x MT MFMA.
// ---------------------------------------------------------------------------
template<int CIN, int COUTP, bool RELU, bool FINAL>
__global__ __launch_bounds__(256) void conv_layer_k(
    const f16* __restrict__ ain, const f16* __restrict__ wt,
    const float* __restrict__ bias, f16* __restrict__ aout,
    float* __restrict__ fout)
{
  constexpr int MT = COUTP / 16;
  constexpr int NCK = CIN / 32;
  constexpr int NSTAGE = NCK * 9;
  constexpr int BUFH = 324 * 32 + 544;     // halves; 544 = slack for overflow lanes
  __shared__ f16 hal[2 * BUFH];            // 43,648 B

  const int tid = threadIdx.x;
  const int bid = xcd_swizzle(blockIdx.x);
  const int b = bid >> 8;
  const int d1 = (bid >> 4) & 15, d2 = bid & 15;
  const int lane = tid & 63, wave = tid >> 6;
  const int lm = lane & 15, kp = lane >> 4;

  f32x4 acc[MT][4] = {};

  auto issue = [&](int s) {
    int ck = (NCK == 2 && s >= 9) ? 1 : 0;
    int e = s - ck * 9;
    int e1 = e / 3, e2 = e - e1 * 3;
    int dd1 = d1 + e1 - 1, dd2 = d2 + e2 - 1;
    bool pok = ((unsigned)dd1 < 16u) & ((unsigned)dd2 < 16u);
    const f16* pbase = ain + (size_t)(((b * 16 + dd1) * 16 + dd2) * 256) * CIN + ck * 32;
    f16* wbase = hal + (s & 1) * BUFH + wave * (81 * 32);
    #pragma unroll
    for (int j = 0; j < 6; ++j) {
      int t = j * 64 + lane;
      int cell = wave * 81 + (t >> 2);       // may exceed own range: duplicates
      int q = t & 3;                          //   next wave's cells (same data)
      int h3 = cell / 18;
      int h4 = cell - h3 * 18;
      int dd3 = h3 - 1, dd4 = h4 - 1;
      bool ok = pok & ((unsigned)dd3 < 16u) & ((unsigned)dd4 < 16u);
      if (ok) {
        GLD16(pbase + (dd3 * 16 + dd4) * CIN + q * 8, wbase + j * 512);
      } else {
        *(int4v*)(wbase + j * 512 + lane * 8) = (int4v){0, 0, 0, 0};
      }
    }
  };

  issue(0);
  for (int s = 0; s < NSTAGE; ++s) {
    if (s + 1 < NSTAGE) {
      issue(s + 1);
      asm volatile("s_waitcnt vmcnt(6) lgkmcnt(0)" ::: "memory");
    } else {
      asm volatile("s_waitcnt vmcnt(0) lgkmcnt(0)" ::: "memory");
    }
    __builtin_amdgcn_sched_barrier(0);
    __builtin_amdgcn_s_barrier();
    __builtin_amdgcn_sched_barrier(0);

    int ck = (NCK == 2 && s >= 9) ? 1 : 0;
    int e = s - ck * 9;
    const f16* buf = hal + (s & 1) * BUFH;
    #pragma unroll
    for (int o3 = 0; o3 < 3; ++o3) {
      #pragma unroll
      for (int o4 = 0; o4 < 3; ++o4) {
        int tap = (e * 3 + o3) * 3 + o4;
        f16x8 a[MT];
        #pragma unroll
        for (int mt = 0; mt < MT; ++mt)
          a[mt] = *(const f16x8*)(wt + (size_t)(tap * COUTP + mt * 16 + lm) * CIN + ck * 32 + kp * 8);
        #pragma unroll
        for (int nt = 0; nt < 4; ++nt) {
          const f16x8 bf = *(const f16x8*)(buf + ((wave * 4 + nt + o3) * 18 + lm + o4) * 32 + kp * 8);
          #pragma unroll
          for (int mt = 0; mt < MT; ++mt)
            acc[mt][nt] = __builtin_amdgcn_mfma_f32_16x16x32_f16(a[mt], bf, acc[mt][nt], 0, 0, 0);
        }
      }
    }
    __builtin_amdgcn_sched_barrier(0);
    __builtin_amdgcn_s_barrier();
    __builtin_amdgcn_sched_barrier(0);
  }

  if (FINAL) {
    if (kp == 0) {
      float bv = bias[0];
      #pragma unroll
      for (int nt = 0; nt < 4; ++nt) {
        int d3 = wave * 4 + nt;
        fout[bid * 256 + d3 * 16 + lm] = acc[0][nt][0] + bv;
      }
    }
  } else {
    #pragma unroll
    for (int mt = 0; mt < MT; ++mt) {
      int co = mt * 16 + kp * 4;
      const float* bp = bias + co;
      #pragma unroll
      for (int nt = 0; nt < 4; ++nt) {
        int d3 = wave * 4 + nt;
        f16x4 pk;
        #pragma unroll
        for (int r = 0; r < 4; ++r) {
          float v = acc[mt][nt][r] + bp[r];
          if (RELU) v = fmaxf(v, 0.f);
          pk[r] = (f16)v;
        }
        *(f16x4*)(aout + (size_t)(bid * 256 + d3 * 16 + lm) * COUTP + co) = pk;
      }
    }
  }
}

extern "C" void kernel_launch(void* const* d_in, const int* in_sizes, int n_in,
                              void* d_out, int out_size, void* d_ws, size_t ws_size,
                              hipStream_t stream)
{
  (void)in_sizes; (void)n_in; (void)out_size; (void)ws_size;
  const float* x  = (const float*)d_in[0];
  const float* w1 = (const float*)d_in[1];
  const float* b1 = (const float*)d_in[2];
  const float* w2 = (const float*)d_in[3];
  const float* b2 = (const float*)d_in[4];
  const float* w3 = (const float*)d_in[5];
  const float* b3 = (const float*)d_in[6];
  const float* w4 = (const float*)d_in[7];
  const float* b4 = (const float*)d_in[8];

  f16* ws  = (f16*)d_ws;
  f16* w1t = ws;
  f16* w2t = ws + 3072;
  f16* w3t = ws + 168960;
  f16* w4t = ws + 334848;
  f16* a1  = ws + 376320;
  f16* a2  = a1 + (size_t)2 * SP * 32;
  f16* a3  = a1;                      // a1 dead after layer 2 reads it
  float* out = (float*)d_out;

  wtrans_k<<<1470, 256, 0, stream>>>(w1, w2, w3, w4, ws);
  conv_l1_k<<<512, 256, 0, stream>>>(x, w1t, b1, a1);
  conv_layer_k<32, 64, true,  false><<<512, 256, 0, stream>>>(a1, w2t, b2, a2, nullptr);
  conv_layer_k<64, 32, true,  false><<<512, 256, 0, stream>>>(a2, w3t, b3, a3, nullptr);
  conv_layer_k<32, 16, false, true ><<<512, 256, 0, stream>>>(a3, w4t, b4, nullptr, out);
}